// Round 1
// baseline (1312.477 us; speedup 1.0000x reference)
//
#include <hip/hip_runtime.h>
#include <math.h>

typedef float f32x4 __attribute__((ext_vector_type(4)));
typedef unsigned int u32x4 __attribute__((ext_vector_type(4)));
typedef unsigned short u16x4 __attribute__((ext_vector_type(4)));
typedef __bf16 bf16x8 __attribute__((ext_vector_type(8)));

#define SCALE_Q 0.08838834764831845f   // 1/sqrt(128)

__device__ __forceinline__ float bf2f(unsigned short u) {
  unsigned int x = ((unsigned int)u) << 16;
  return __builtin_bit_cast(float, x);
}
__device__ __forceinline__ unsigned short f2bf(float f) {
  unsigned int u = __builtin_bit_cast(unsigned int, f);
  u += 0x7fffu + ((u >> 16) & 1u);
  return (unsigned short)(u >> 16);
}

// ---------------- fp32 -> bf16 conversion (vectorized) ----------------
__global__ __launch_bounds__(256) void cvt_bf16(const float* __restrict__ in,
                                                unsigned short* __restrict__ out, int n4) {
  int i = blockIdx.x * 256 + threadIdx.x;
  if (i >= n4) return;
  f32x4 v = *(const f32x4*)(in + (size_t)i * 4);
  u16x4 o;
  o[0] = f2bf(v[0]); o[1] = f2bf(v[1]); o[2] = f2bf(v[2]); o[3] = f2bf(v[3]);
  *(u16x4*)(out + (size_t)i * 4) = o;
}

// ---------------- GEMM  C[M,N] = A[M,K] * B[N,K]^T  (bf16 in, fp32 acc) -------
// 128x128 tile, BK=32, 4 waves (2x2), each wave 64x64 via 4x4 frags of 16x16x32.
template <int BF16OUT>
__global__ __launch_bounds__(256) void gemm_nt(const unsigned short* __restrict__ A,
                                               const unsigned short* __restrict__ B,
                                               float* __restrict__ Cf,
                                               unsigned short* __restrict__ Cb,
                                               int M, int N, int K) {
  __shared__ __align__(16) unsigned short As[128 * 32];
  __shared__ __align__(16) unsigned short Bs[128 * 32];
  const int tid = threadIdx.x, lane = tid & 63, wv = tid >> 6;
  const int m0 = blockIdx.y * 128, n0 = blockIdx.x * 128;
  const int wm = (wv >> 1) * 64, wn = (wv & 1) * 64;
  const int l16 = lane & 15, g16 = lane >> 4;

  f32x4 acc[4][4] = {};

  // staging: thread covers rows (tid>>2) and 64+(tid>>2), cols (tid&3)*8..+8
  const int srow = tid >> 2, scol = (tid & 3) * 8;
  const unsigned short* ag0 = A + (size_t)(m0 + srow) * K + scol;
  const unsigned short* ag1 = A + (size_t)(m0 + 64 + srow) * K + scol;
  const unsigned short* bg0 = B + (size_t)(n0 + srow) * K + scol;
  const unsigned short* bg1 = B + (size_t)(n0 + 64 + srow) * K + scol;

  u32x4 av0 = *(const u32x4*)ag0;
  u32x4 av1 = *(const u32x4*)ag1;
  u32x4 bv0 = *(const u32x4*)bg0;
  u32x4 bv1 = *(const u32x4*)bg1;

  for (int k0 = 0; k0 < K; k0 += 32) {
    __syncthreads();
    *(u32x4*)&As[tid * 8]        = av0;
    *(u32x4*)&As[2048 + tid * 8] = av1;
    *(u32x4*)&Bs[tid * 8]        = bv0;
    *(u32x4*)&Bs[2048 + tid * 8] = bv1;
    __syncthreads();
    if (k0 + 32 < K) {
      av0 = *(const u32x4*)(ag0 + k0 + 32);
      av1 = *(const u32x4*)(ag1 + k0 + 32);
      bv0 = *(const u32x4*)(bg0 + k0 + 32);
      bv1 = *(const u32x4*)(bg1 + k0 + 32);
    }
    bf16x8 af[4], bf[4];
#pragma unroll
    for (int mi = 0; mi < 4; ++mi)
      af[mi] = *(const bf16x8*)&As[(wm + mi * 16 + l16) * 32 + g16 * 8];
#pragma unroll
    for (int ni = 0; ni < 4; ++ni)
      bf[ni] = *(const bf16x8*)&Bs[(wn + ni * 16 + l16) * 32 + g16 * 8];
#pragma unroll
    for (int mi = 0; mi < 4; ++mi)
#pragma unroll
      for (int ni = 0; ni < 4; ++ni)
        acc[mi][ni] = __builtin_amdgcn_mfma_f32_16x16x32_bf16(af[mi], bf[ni], acc[mi][ni], 0, 0, 0);
  }

#pragma unroll
  for (int mi = 0; mi < 4; ++mi)
#pragma unroll
    for (int ni = 0; ni < 4; ++ni) {
      int row = m0 + wm + mi * 16 + g16 * 4;
      int col = n0 + wn + ni * 16 + l16;
#pragma unroll
      for (int r = 0; r < 4; ++r) {
        if (BF16OUT)
          Cb[(size_t)(row + r) * N + col] = f2bf(acc[mi][ni][r]);
        else
          Cf[(size_t)(row + r) * N + col] = acc[mi][ni][r];
      }
    }
}

// ---------------- RoPE + layout: C1[M,6144] -> Q(B,NH,S,HD), K(B,8,S,HD), V ----
__global__ __launch_bounds__(256) void rope_cvt(const unsigned short* __restrict__ C1,
                                                const int* __restrict__ pos_ids,
                                                unsigned short* __restrict__ Qb,
                                                unsigned short* __restrict__ Kb,
                                                unsigned short* __restrict__ Vb) {
  int idx = blockIdx.x * 256 + threadIdx.x;  // total 2*2048*48*64 = 12,582,912
  int i = idx & 63;
  int t = idx >> 6;
  int head = t % 48;
  int m = t / 48;          // 0..4095 == b*2048 + s
  int b = m >> 11, s = m & 2047;
  const unsigned short* src = C1 + (size_t)m * 6144 + head * 128;
  float x1 = bf2f(src[i]), x2 = bf2f(src[i + 64]);
  if (head < 40) {  // rope for q and k heads
    float invf = exp2f((float)i * -0.2076205059304601f);  // 10000^(-i/64)
    float ang = (float)pos_ids[m] * invf;
    float c, sn;
    sincosf(ang, &sn, &c);
    float o1 = x1 * c - x2 * sn;
    float o2 = x2 * c + x1 * sn;
    x1 = o1; x2 = o2;
  }
  unsigned short* dst;
  if (head < 32)
    dst = Qb + ((size_t)(b * 32 + head) * 2048 + s) * 128;
  else if (head < 40)
    dst = Kb + ((size_t)(b * 8 + head - 32) * 2048 + s) * 128;
  else
    dst = Vb + ((size_t)(b * 8 + head - 40) * 2048 + s) * 128;
  dst[i] = f2bf(x1);
  dst[i + 64] = f2bf(x2);
}

// ---------------- Flash attention (causal, GQA), 4 waves, QBLK=64, KVBLK=64 ----
__global__ __launch_bounds__(256) void flash_fwd(const unsigned short* __restrict__ Q,
                                                 const unsigned short* __restrict__ K,
                                                 const unsigned short* __restrict__ V,
                                                 unsigned short* __restrict__ AO) {
  __shared__ __align__(16) unsigned short Ks[64 * 128];   // XOR-swizzled rows
  __shared__ __align__(16) unsigned short VT[128 * 72];   // V transposed, pad 72
  __shared__ __align__(16) unsigned short Pl[4 * 16 * 72];// per-wave P tile
  const int qt = blockIdx.x, h = blockIdx.y, b = blockIdx.z;
  const int tid = threadIdx.x, lane = tid & 63, wv = tid >> 6;
  const int l16 = lane & 15, g16 = lane >> 4;
  const unsigned short* Qp = Q + (size_t)(b * 32 + h) * 2048 * 128;
  const unsigned short* Kp = K + (size_t)(b * 8 + (h >> 2)) * 2048 * 128;
  const unsigned short* Vp = V + (size_t)(b * 8 + (h >> 2)) * 2048 * 128;

  // Q fragments hoisted (wave-local row = l16)
  bf16x8 qf[4];
  {
    int qrow = qt * 64 + wv * 16 + l16;
#pragma unroll
    for (int ks = 0; ks < 4; ++ks)
      qf[ks] = *(const bf16x8*)&Qp[(size_t)qrow * 128 + ks * 32 + g16 * 8];
  }

  float m_r[4] = {-1e30f, -1e30f, -1e30f, -1e30f};
  float l_r[4] = {0.f, 0.f, 0.f, 0.f};
  f32x4 ao[8] = {};

  const int st_row = tid >> 4;        // 0..15
  const int st_cb = (tid & 15) * 16;  // byte col in 256B row

  for (int kb = 0; kb <= qt; ++kb) {
    __syncthreads();  // protect Ks/VT from previous iteration readers
    // stage K tile, swizzled: phys_byte = row*256 + (cb ^ ((row&7)<<4))
#pragma unroll
    for (int p = 0; p < 4; ++p) {
      int row = p * 16 + st_row;
      u32x4 v = *(const u32x4*)&Kp[(size_t)(kb * 64 + row) * 128 + (st_cb >> 1)];
      *(u32x4*)((char*)Ks + row * 256 + (st_cb ^ ((row & 7) << 4))) = v;
    }
    // stage V transposed
#pragma unroll
    for (int p = 0; p < 4; ++p) {
      int row = p * 16 + st_row;  // k index
      u32x4 v = *(const u32x4*)&Vp[(size_t)(kb * 64 + row) * 128 + (st_cb >> 1)];
      const unsigned short* pv8 = (const unsigned short*)&v;
      int d0 = st_cb >> 1;
#pragma unroll
      for (int j = 0; j < 8; ++j) VT[(d0 + j) * 72 + row] = pv8[j];
    }
    __syncthreads();

    // QK^T : S[16q x 64k] per wave
    f32x4 sc[4] = {};
#pragma unroll
    for (int kt = 0; kt < 4; ++kt) {
#pragma unroll
      for (int ks = 0; ks < 4; ++ks) {
        int row = kt * 16 + l16;
        int cb = ks * 64 + g16 * 16;
        bf16x8 kf = *(const bf16x8*)((const char*)Ks + row * 256 + (cb ^ ((row & 7) << 4)));
        sc[kt] = __builtin_amdgcn_mfma_f32_16x16x32_bf16(qf[ks], kf, sc[kt], 0, 0, 0);
      }
    }

    // scale + causal mask
    int qrow0 = qt * 64 + wv * 16 + g16 * 4;
    float p_[4][4];
#pragma unroll
    for (int kt = 0; kt < 4; ++kt)
#pragma unroll
      for (int r = 0; r < 4; ++r) {
        float s = sc[kt][r] * SCALE_Q;
        int kc = kb * 64 + kt * 16 + l16;
        p_[kt][r] = (kc <= qrow0 + r) ? s : -INFINITY;
      }

    // online softmax (row spread over 16-lane group)
#pragma unroll
    for (int r = 0; r < 4; ++r) {
      float mx = fmaxf(fmaxf(p_[0][r], p_[1][r]), fmaxf(p_[2][r], p_[3][r]));
#pragma unroll
      for (int off = 8; off; off >>= 1) mx = fmaxf(mx, __shfl_xor(mx, off));
      float mnew = fmaxf(m_r[r], mx);
      float resc = __expf(m_r[r] - mnew);
      m_r[r] = mnew;
      float rsum = 0.f;
#pragma unroll
      for (int kt = 0; kt < 4; ++kt) {
        float e = __expf(p_[kt][r] - mnew);
        p_[kt][r] = e;
        rsum += e;
      }
#pragma unroll
      for (int off = 8; off; off >>= 1) rsum += __shfl_xor(rsum, off);
      l_r[r] = l_r[r] * resc + rsum;
#pragma unroll
      for (int dt = 0; dt < 8; ++dt) ao[dt][r] *= resc;
    }

    // P -> LDS (per-wave slice), re-layout for PV A-operand
#pragma unroll
    for (int kt = 0; kt < 4; ++kt)
#pragma unroll
      for (int r = 0; r < 4; ++r)
        Pl[(wv * 16 + g16 * 4 + r) * 72 + kt * 16 + l16] = f2bf(p_[kt][r]);

    bf16x8 pa[2];
#pragma unroll
    for (int kc = 0; kc < 2; ++kc)
      pa[kc] = *(const bf16x8*)&Pl[(wv * 16 + l16) * 72 + kc * 32 + g16 * 8];

    // PV: O[16q x 128d] accumulate
#pragma unroll
    for (int dt = 0; dt < 8; ++dt) {
#pragma unroll
      for (int kc = 0; kc < 2; ++kc) {
        bf16x8 vf = *(const bf16x8*)&VT[(dt * 16 + l16) * 72 + kc * 32 + g16 * 8];
        ao[dt] = __builtin_amdgcn_mfma_f32_16x16x32_bf16(pa[kc], vf, ao[dt], 0, 0, 0);
      }
    }
  }

  // write normalized output: AO[b, q, h*128 + d]
  int qrow = qt * 64 + wv * 16 + g16 * 4;
#pragma unroll
  for (int r = 0; r < 4; ++r) {
    float inv = 1.0f / l_r[r];
#pragma unroll
    for (int dt = 0; dt < 8; ++dt)
      AO[((size_t)b * 2048 + qrow + r) * 4096 + h * 128 + dt * 16 + l16] =
          f2bf(ao[dt][r] * inv);
  }
}

// ---------------- suppression fixup: recompute row tgt_pos[b] for every head ---
__global__ __launch_bounds__(256) void suppress_fix(const unsigned short* __restrict__ Q,
                                                    const unsigned short* __restrict__ K,
                                                    const unsigned short* __restrict__ V,
                                                    const int* __restrict__ tgt,
                                                    const int* __restrict__ subj,
                                                    unsigned short* __restrict__ AO) {
  const int h = blockIdx.x, b = blockIdx.y;
  const int tid = threadIdx.x, lane = tid & 63, wv = tid >> 6;
  __shared__ float qv[128];
  __shared__ float warr[2048];
  __shared__ float sred[4];
  int row = tgt[b];
  const unsigned short* Qp = Q + ((size_t)(b * 32 + h) * 2048 + row) * 128;
  const unsigned short* Kp = K + (size_t)(b * 8 + (h >> 2)) * 2048 * 128;
  const unsigned short* Vp = V + (size_t)(b * 8 + (h >> 2)) * 2048 * 128;
  if (tid < 128) qv[tid] = bf2f(Qp[tid]) * SCALE_Q;
  __syncthreads();
  int nk = row + 1;
  float lmax = -1e30f;
  for (int j = tid; j < nk; j += 256) {
    const unsigned short* kr = Kp + (size_t)j * 128;
    float s = 0.f;
    for (int d = 0; d < 128; d += 8) {
      u32x4 kv = *(const u32x4*)&kr[d];
      const unsigned short* kk = (const unsigned short*)&kv;
#pragma unroll
      for (int e = 0; e < 8; ++e) s += qv[d + e] * bf2f(kk[e]);
    }
    warr[j] = s;
    lmax = fmaxf(lmax, s);
  }
  // block max
#pragma unroll
  for (int off = 32; off; off >>= 1) lmax = fmaxf(lmax, __shfl_xor(lmax, off));
  if (lane == 0) sred[wv] = lmax;
  __syncthreads();
  float mx = fmaxf(fmaxf(sred[0], sred[1]), fmaxf(sred[2], sred[3]));
  __syncthreads();
  // exp, denominator (unsuppressed), numerator weights (suppressed)
  float lsum = 0.f;
  for (int j = tid; j < nk; j += 256) {
    float w = __expf(warr[j] - mx);
    lsum += w;
    float f = 1.f;
#pragma unroll
    for (int i2 = 0; i2 < 8; ++i2)
      if (subj[b * 8 + i2] == j) f *= 0.1f;  // handles duplicate indices
    warr[j] = w * f;
  }
#pragma unroll
  for (int off = 32; off; off >>= 1) lsum += __shfl_xor(lsum, off);
  if (lane == 0) sred[wv] = lsum;
  __syncthreads();
  float tot = sred[0] + sred[1] + sred[2] + sred[3];
  if (tid < 128) {
    float acc = 0.f;
    for (int j = 0; j < nk; ++j) acc += warr[j] * bf2f(Vp[(size_t)j * 128 + tid]);
    AO[((size_t)b * 2048 + row) * 4096 + h * 128 + tid] = f2bf(acc / tot);
  }
}

// ---------------- launch ----------------
extern "C" void kernel_launch(void* const* d_in, const int* in_sizes, int n_in,
                              void* d_out, int out_size, void* d_ws, size_t ws_size,
                              hipStream_t stream) {
  const float* hidden = (const float*)d_in[0];
  const float* Wq = (const float*)d_in[1];
  const float* Wk = (const float*)d_in[2];
  const float* Wv = (const float*)d_in[3];
  const float* Wo = (const float*)d_in[4];
  // d_in[5] = attention_mask: deterministically causal, not read
  const int* pos = (const int*)d_in[6];
  const int* tgt = (const int*)d_in[7];
  const int* subj = (const int*)d_in[8];
  float* out = (float*)d_out;

  unsigned short* ws = (unsigned short*)d_ws;
  unsigned short* Xb    = ws;                       // 16,777,216
  unsigned short* Wqkvb = Xb + (size_t)16777216;    // 25,165,824
  unsigned short* Wob   = Wqkvb + (size_t)25165824; // 16,777,216
  unsigned short* C1    = Wob + (size_t)16777216;   // 25,165,824
  unsigned short* Qb    = C1 + (size_t)25165824;    // 16,777,216
  unsigned short* Kb    = Qb + (size_t)16777216;    //  4,194,304
  unsigned short* Vb    = Kb + (size_t)4194304;     //  4,194,304
  unsigned short* AO    = Vb + (size_t)4194304;     // 16,777,216

  // fp32 -> bf16
  cvt_bf16<<<16384, 256, 0, stream>>>(hidden, Xb, 4194304);
  cvt_bf16<<<16384, 256, 0, stream>>>(Wq, Wqkvb, 4194304);
  cvt_bf16<<<4096, 256, 0, stream>>>(Wk, Wqkvb + (size_t)16777216, 1048576);
  cvt_bf16<<<4096, 256, 0, stream>>>(Wv, Wqkvb + (size_t)20971520, 1048576);
  cvt_bf16<<<16384, 256, 0, stream>>>(Wo, Wob, 4194304);

  // QKV projection: [4096,4096] x [6144,4096]^T -> bf16 C1
  gemm_nt<1><<<dim3(48, 32), 256, 0, stream>>>(Xb, Wqkvb, nullptr, C1, 4096, 6144, 4096);

  // RoPE + head-major layout
  rope_cvt<<<49152, 256, 0, stream>>>(C1, pos, Qb, Kb, Vb);

  // flash attention
  flash_fwd<<<dim3(32, 32, 2), 256, 0, stream>>>(Qb, Kb, Vb, AO);

  // suppression fixup (64 rows recomputed exactly)
  suppress_fix<<<dim3(32, 2), 256, 0, stream>>>(Qb, Kb, Vb, tgt, subj, AO);

  // output projection: [4096,4096] x [4096,4096]^T -> fp32 out
  gemm_nt<0><<<dim3(32, 32), 256, 0, stream>>>(AO, Wob, out, nullptr, 4096, 4096, 4096);
}

// Round 2
// 795.390 us; speedup vs baseline: 1.6501x; 1.6501x over previous
//
#include <hip/hip_runtime.h>
#include <math.h>

typedef float f32x4 __attribute__((ext_vector_type(4)));
typedef unsigned int u32x4 __attribute__((ext_vector_type(4)));
typedef unsigned short u16x4 __attribute__((ext_vector_type(4)));
typedef __bf16 bf16x8 __attribute__((ext_vector_type(8)));

#define SCALE_Q 0.08838834764831845f   // 1/sqrt(128)

__device__ __forceinline__ float bf2f(unsigned short u) {
  unsigned int x = ((unsigned int)u) << 16;
  return __builtin_bit_cast(float, x);
}
__device__ __forceinline__ unsigned short f2bf(float f) {
  unsigned int u = __builtin_bit_cast(unsigned int, f);
  u += 0x7fffu + ((u >> 16) & 1u);
  return (unsigned short)(u >> 16);
}

// async global->LDS, 16B per lane; lds dest must be wave-uniform base (HW adds lane*16)
__device__ __forceinline__ void gload_lds16(const unsigned short* g, unsigned short* l) {
  __builtin_amdgcn_global_load_lds((const __attribute__((address_space(1))) unsigned int*)g,
                                   (__attribute__((address_space(3))) unsigned int*)l,
                                   16, 0, 0);
}

// ---------------- fp32 -> bf16 conversion (vectorized) ----------------
__global__ __launch_bounds__(256) void cvt_bf16(const float* __restrict__ in,
                                                unsigned short* __restrict__ out, int n4) {
  int i = blockIdx.x * 256 + threadIdx.x;
  if (i >= n4) return;
  f32x4 v = *(const f32x4*)(in + (size_t)i * 4);
  u16x4 o;
  o[0] = f2bf(v[0]); o[1] = f2bf(v[1]); o[2] = f2bf(v[2]); o[3] = f2bf(v[3]);
  *(u16x4*)(out + (size_t)i * 4) = o;
}

// ---------------- GEMM  C[M,N] = A[M,K] * B[N,K]^T  (bf16 in, fp32 acc) -------
// 128x128 tile, BK=32, 4 waves (2x2), global_load_lds width-16 staging (m97).
template <int BF16OUT>
__global__ __launch_bounds__(256) void gemm_nt(const unsigned short* __restrict__ A,
                                               const unsigned short* __restrict__ B,
                                               float* __restrict__ Cf,
                                               unsigned short* __restrict__ Cb,
                                               int M, int N, int K) {
  __shared__ __align__(16) unsigned short As[128 * 32];
  __shared__ __align__(16) unsigned short Bs[128 * 32];
  const int tid = threadIdx.x, lane = tid & 63, wv = tid >> 6;
  const int m0 = blockIdx.y * 128, n0 = blockIdx.x * 128;
  const int wm = (wv >> 1) * 64, wn = (wv & 1) * 64;
  const int l16 = lane & 15, g16 = lane >> 4;

  f32x4 acc[4][4] = {};

  // gload_lds source coords: wave w covers LDS bytes [w*2048, w*2048+2048)
  // inst i in {0,1}: row = w*32 + i*16 + (lane>>2), col = (lane&3)*8 elems
  const int lrow = wv * 32 + (lane >> 2);
  const int lcol = (lane & 3) * 8;
  const unsigned short* Ag0 = A + (size_t)(m0 + lrow) * K + lcol;
  const unsigned short* Ag1 = A + (size_t)(m0 + lrow + 16) * K + lcol;
  const unsigned short* Bg0 = B + (size_t)(n0 + lrow) * K + lcol;
  const unsigned short* Bg1 = B + (size_t)(n0 + lrow + 16) * K + lcol;
  unsigned short* Al = As + wv * 1024;  // elems (2048 B)
  unsigned short* Bl = Bs + wv * 1024;

  for (int k0 = 0; k0 < K; k0 += 32) {
    __syncthreads();
    gload_lds16(Ag0 + k0, Al);
    gload_lds16(Ag1 + k0, Al + 512);
    gload_lds16(Bg0 + k0, Bl);
    gload_lds16(Bg1 + k0, Bl + 512);
    __syncthreads();
    bf16x8 af[4], bf[4];
#pragma unroll
    for (int mi = 0; mi < 4; ++mi)
      af[mi] = *(const bf16x8*)&As[(wm + mi * 16 + l16) * 32 + g16 * 8];
#pragma unroll
    for (int ni = 0; ni < 4; ++ni)
      bf[ni] = *(const bf16x8*)&Bs[(wn + ni * 16 + l16) * 32 + g16 * 8];
#pragma unroll
    for (int mi = 0; mi < 4; ++mi)
#pragma unroll
      for (int ni = 0; ni < 4; ++ni)
        acc[mi][ni] = __builtin_amdgcn_mfma_f32_16x16x32_bf16(af[mi], bf[ni], acc[mi][ni], 0, 0, 0);
  }

#pragma unroll
  for (int mi = 0; mi < 4; ++mi)
#pragma unroll
    for (int ni = 0; ni < 4; ++ni) {
      int row = m0 + wm + mi * 16 + g16 * 4;
      int col = n0 + wn + ni * 16 + l16;
#pragma unroll
      for (int r = 0; r < 4; ++r) {
        if (BF16OUT)
          Cb[(size_t)(row + r) * N + col] = f2bf(acc[mi][ni][r]);
        else
          Cf[(size_t)(row + r) * N + col] = acc[mi][ni][r];
      }
    }
}

// ---------------- RoPE + layout: C1[M,6144] -> Q(B,32,S,HD), K(B,8,S,HD) -------
__global__ __launch_bounds__(256) void rope_cvt(const unsigned short* __restrict__ C1,
                                                const int* __restrict__ pos_ids,
                                                unsigned short* __restrict__ Qb,
                                                unsigned short* __restrict__ Kb) {
  int idx = blockIdx.x * 256 + threadIdx.x;  // total 4096*40*64 = 10,485,760
  int i = idx & 63;
  int t = idx >> 6;
  int head = t % 40;
  int m = t / 40;          // 0..4095 == b*2048 + s
  int b = m >> 11, s = m & 2047;
  const unsigned short* src = C1 + (size_t)m * 6144 + head * 128;
  float x1 = bf2f(src[i]), x2 = bf2f(src[i + 64]);
  float invf = exp2f((float)i * -0.2076205059304601f);  // 10000^(-i/64)
  float ang = (float)pos_ids[m] * invf;
  float c, sn;
  sincosf(ang, &sn, &c);
  float o1 = x1 * c - x2 * sn;
  float o2 = x2 * c + x1 * sn;
  unsigned short* dst;
  if (head < 32)
    dst = Qb + ((size_t)(b * 32 + head) * 2048 + s) * 128;
  else
    dst = Kb + ((size_t)(b * 8 + head - 32) * 2048 + s) * 128;
  dst[i] = f2bf(o1);
  dst[i + 64] = f2bf(o2);
}

// ---------------- V transpose: C1 V-heads -> Vt[b,kvh][d=128][s=2048] ----------
__global__ __launch_bounds__(256) void vtrans(const unsigned short* __restrict__ C1,
                                              unsigned short* __restrict__ Vt) {
  __shared__ __align__(16) unsigned short T[64 * 72];
  const int s0 = blockIdx.x * 64, d0 = blockIdx.y * 64, bh = blockIdx.z;  // bh=b*8+kvh
  const int t = threadIdx.x;
  {
    int sl = t >> 2, c16 = (t & 3) * 16;
    const unsigned short* src =
        C1 + (size_t)((bh >> 3) * 2048 + s0 + sl) * 6144 + 5120 + (bh & 7) * 128 + d0 + c16;
    u32x4 a0 = *(const u32x4*)src;
    u32x4 a1 = *(const u32x4*)(src + 8);
    *(u32x4*)&T[sl * 72 + c16] = a0;
    *(u32x4*)&T[sl * 72 + c16 + 8] = a1;
  }
  __syncthreads();
  {
    int dl = t >> 2, s16 = (t & 3) * 16;
    unsigned short* dst = Vt + ((size_t)bh * 128 + d0 + dl) * 2048 + s0 + s16;
    u16x4 o[4];
#pragma unroll
    for (int j = 0; j < 16; ++j) ((unsigned short*)o)[j] = T[(s16 + j) * 72 + dl];
#pragma unroll
    for (int q = 0; q < 4; ++q) *(u16x4*)(dst + q * 4) = o[q];
  }
}

// ---------------- Flash attention (causal, GQA), 4 waves, QBLK=64, KVBLK=64 ----
// paired q-tiles {31-x, x} for load balance; VT staged from pre-transposed Vt.
__global__ __launch_bounds__(256) void flash_fwd(const unsigned short* __restrict__ Q,
                                                 const unsigned short* __restrict__ K,
                                                 const unsigned short* __restrict__ Vt,
                                                 unsigned short* __restrict__ AO) {
  __shared__ __align__(16) unsigned short Ks[64 * 128];  // [k][d], 256B rows, XOR swz
  __shared__ __align__(16) unsigned short VT[128 * 64];  // [d][k], 128B rows, XOR swz
  __shared__ __align__(16) unsigned short Pl[64 * 72];   // [q][k] pad 72
  const int qpair = blockIdx.x, h = blockIdx.y, b = blockIdx.z;
  const int tid = threadIdx.x, lane = tid & 63, wv = tid >> 6;
  const int l16 = lane & 15, g16 = lane >> 4;
  const unsigned short* Qp = Q + (size_t)(b * 32 + h) * 2048 * 128;
  const unsigned short* Kp = K + (size_t)(b * 8 + (h >> 2)) * 2048 * 128;
  const unsigned short* Vp = Vt + (size_t)(b * 8 + (h >> 2)) * 128 * 2048;

  const int st_row = tid >> 4;        // 0..15
  const int st_cb = (tid & 15) * 16;  // byte col in 256B K row
  const int vd = tid >> 1;            // 0..127  (V d-row)
  const int vh = tid & 1;             // 64B half of 128B V row

  for (int pass = 0; pass < 2; ++pass) {
    const int qt = pass == 0 ? (31 - qpair) : qpair;

    bf16x8 qf[4];
    {
      int qrow = qt * 64 + wv * 16 + l16;
#pragma unroll
      for (int ks = 0; ks < 4; ++ks)
        qf[ks] = *(const bf16x8*)&Qp[(size_t)qrow * 128 + ks * 32 + g16 * 8];
    }

    float m_r[4] = {-1e30f, -1e30f, -1e30f, -1e30f};
    float l_r[4] = {0.f, 0.f, 0.f, 0.f};
    f32x4 ao[8] = {};

    for (int kb = 0; kb <= qt; ++kb) {
      __syncthreads();  // protect Ks/VT from previous iteration/pass readers
      // stage K tile: phys = row*256 + (cb ^ ((row&7)<<4))
#pragma unroll
      for (int p = 0; p < 4; ++p) {
        int row = p * 16 + st_row;
        u32x4 v = *(const u32x4*)&Kp[(size_t)(kb * 64 + row) * 128 + (st_cb >> 1)];
        *(u32x4*)((char*)Ks + row * 256 + (st_cb ^ ((row & 7) << 4))) = v;
      }
      // stage V tile from Vt (rows are d, 64 k-elems = 128B, XOR swz bits 4-6)
#pragma unroll
      for (int j = 0; j < 4; ++j) {
        u32x4 v = *(const u32x4*)&Vp[(size_t)vd * 2048 + kb * 64 + vh * 32 + j * 8];
        *(u32x4*)((char*)VT + vd * 128 + ((vh * 64 + j * 16) ^ ((vd & 7) << 4))) = v;
      }
      __syncthreads();

      // QK^T : S[16q x 64k] per wave
      f32x4 sc[4] = {};
#pragma unroll
      for (int kt = 0; kt < 4; ++kt) {
#pragma unroll
        for (int ks = 0; ks < 4; ++ks) {
          int row = kt * 16 + l16;
          int cb = ks * 64 + g16 * 16;
          bf16x8 kf = *(const bf16x8*)((const char*)Ks + row * 256 + (cb ^ ((row & 7) << 4)));
          sc[kt] = __builtin_amdgcn_mfma_f32_16x16x32_bf16(qf[ks], kf, sc[kt], 0, 0, 0);
        }
      }

      // scale + causal mask
      int qrow0 = qt * 64 + wv * 16 + g16 * 4;
      float p_[4][4];
#pragma unroll
      for (int kt = 0; kt < 4; ++kt)
#pragma unroll
        for (int r = 0; r < 4; ++r) {
          float s = sc[kt][r] * SCALE_Q;
          int kc = kb * 64 + kt * 16 + l16;
          p_[kt][r] = (kc <= qrow0 + r) ? s : -INFINITY;
        }

      // online softmax (row spread over 16-lane group)
#pragma unroll
      for (int r = 0; r < 4; ++r) {
        float mx = fmaxf(fmaxf(p_[0][r], p_[1][r]), fmaxf(p_[2][r], p_[3][r]));
#pragma unroll
        for (int off = 8; off; off >>= 1) mx = fmaxf(mx, __shfl_xor(mx, off));
        float mnew = fmaxf(m_r[r], mx);
        float resc = __expf(m_r[r] - mnew);
        m_r[r] = mnew;
        float rsum = 0.f;
#pragma unroll
        for (int kt = 0; kt < 4; ++kt) {
          float e = __expf(p_[kt][r] - mnew);
          p_[kt][r] = e;
          rsum += e;
        }
#pragma unroll
        for (int off = 8; off; off >>= 1) rsum += __shfl_xor(rsum, off);
        l_r[r] = l_r[r] * resc + rsum;
#pragma unroll
        for (int dt = 0; dt < 8; ++dt) ao[dt][r] *= resc;
      }

      // P -> LDS (per-wave slice), re-layout for PV A-operand
#pragma unroll
      for (int kt = 0; kt < 4; ++kt)
#pragma unroll
        for (int r = 0; r < 4; ++r)
          Pl[(wv * 16 + g16 * 4 + r) * 72 + kt * 16 + l16] = f2bf(p_[kt][r]);

      bf16x8 pa[2];
#pragma unroll
      for (int kc = 0; kc < 2; ++kc)
        pa[kc] = *(const bf16x8*)&Pl[(wv * 16 + l16) * 72 + kc * 32 + g16 * 8];

      // PV: O[16q x 128d] accumulate; VT read with matching XOR swz
#pragma unroll
      for (int dt = 0; dt < 8; ++dt) {
#pragma unroll
        for (int kc = 0; kc < 2; ++kc) {
          bf16x8 vf = *(const bf16x8*)((const char*)VT + (dt * 16 + l16) * 128 +
                                       ((kc * 64 + g16 * 16) ^ ((l16 & 7) << 4)));
          ao[dt] = __builtin_amdgcn_mfma_f32_16x16x32_bf16(pa[kc], vf, ao[dt], 0, 0, 0);
        }
      }
    }

    // write normalized output: AO[b, q, h*128 + d]
    int qrow = qt * 64 + wv * 16 + g16 * 4;
#pragma unroll
    for (int r = 0; r < 4; ++r) {
      float inv = 1.0f / l_r[r];
#pragma unroll
      for (int dt = 0; dt < 8; ++dt)
        AO[((size_t)b * 2048 + qrow + r) * 4096 + h * 128 + dt * 16 + l16] =
            f2bf(ao[dt][r] * inv);
    }
  }
}

// ---------------- suppression fixup: recompute row tgt_pos[b] for every head ---
__global__ __launch_bounds__(256) void suppress_fix(const unsigned short* __restrict__ Q,
                                                    const unsigned short* __restrict__ K,
                                                    const unsigned short* __restrict__ Vt,
                                                    const int* __restrict__ tgt,
                                                    const int* __restrict__ subj,
                                                    unsigned short* __restrict__ AO) {
  const int h = blockIdx.x, b = blockIdx.y;
  const int tid = threadIdx.x, lane = tid & 63, wv = tid >> 6;
  __shared__ float qv[128];
  __shared__ float warr[2048];
  __shared__ float sred[4];
  int row = tgt[b];
  const unsigned short* Qp = Q + ((size_t)(b * 32 + h) * 2048 + row) * 128;
  const unsigned short* Kp = K + (size_t)(b * 8 + (h >> 2)) * 2048 * 128;
  const unsigned short* Vp = Vt + (size_t)(b * 8 + (h >> 2)) * 128 * 2048;
  if (tid < 128) qv[tid] = bf2f(Qp[tid]) * SCALE_Q;
  __syncthreads();
  int nk = row + 1;
  float lmax = -1e30f;
  for (int j = tid; j < nk; j += 256) {
    const unsigned short* kr = Kp + (size_t)j * 128;
    float s = 0.f;
    for (int d = 0; d < 128; d += 8) {
      u32x4 kv = *(const u32x4*)&kr[d];
      const unsigned short* kk = (const unsigned short*)&kv;
#pragma unroll
      for (int e = 0; e < 8; ++e) s += qv[d + e] * bf2f(kk[e]);
    }
    warr[j] = s;
    lmax = fmaxf(lmax, s);
  }
#pragma unroll
  for (int off = 32; off; off >>= 1) lmax = fmaxf(lmax, __shfl_xor(lmax, off));
  if (lane == 0) sred[wv] = lmax;
  __syncthreads();
  float mx = fmaxf(fmaxf(sred[0], sred[1]), fmaxf(sred[2], sred[3]));
  __syncthreads();
  float lsum = 0.f;
  for (int j = tid; j < nk; j += 256) {
    float w = __expf(warr[j] - mx);
    lsum += w;
    float f = 1.f;
#pragma unroll
    for (int i2 = 0; i2 < 8; ++i2)
      if (subj[b * 8 + i2] == j) f *= 0.1f;  // handles duplicate indices
    warr[j] = w * f;
  }
#pragma unroll
  for (int off = 32; off; off >>= 1) lsum += __shfl_xor(lsum, off);
  if (lane == 0) sred[wv] = lsum;
  __syncthreads();
  float tot = sred[0] + sred[1] + sred[2] + sred[3];
  if (tid < 128) {
    float acc = 0.f;
    const unsigned short* vr = Vp + (size_t)tid * 2048;  // row d=tid, contiguous k
    int nk8 = nk & ~7;
    for (int j0 = 0; j0 < nk8; j0 += 8) {
      u32x4 vv = *(const u32x4*)&vr[j0];
      const unsigned short* v8 = (const unsigned short*)&vv;
#pragma unroll
      for (int e = 0; e < 8; ++e) acc += warr[j0 + e] * bf2f(v8[e]);
    }
    for (int j = nk8; j < nk; ++j) acc += warr[j] * bf2f(vr[j]);
    AO[((size_t)b * 2048 + row) * 4096 + h * 128 + tid] = f2bf(acc / tot);
  }
}

// ---------------- launch ----------------
extern "C" void kernel_launch(void* const* d_in, const int* in_sizes, int n_in,
                              void* d_out, int out_size, void* d_ws, size_t ws_size,
                              hipStream_t stream) {
  const float* hidden = (const float*)d_in[0];
  const float* Wq = (const float*)d_in[1];
  const float* Wk = (const float*)d_in[2];
  const float* Wv = (const float*)d_in[3];
  const float* Wo = (const float*)d_in[4];
  // d_in[5] = attention_mask: deterministically causal, not read
  const int* pos = (const int*)d_in[6];
  const int* tgt = (const int*)d_in[7];
  const int* subj = (const int*)d_in[8];
  float* out = (float*)d_out;

  unsigned short* ws = (unsigned short*)d_ws;
  unsigned short* Xb    = ws;                       // 16,777,216
  unsigned short* Wqkvb = Xb + (size_t)16777216;    // 25,165,824
  unsigned short* Wob   = Wqkvb + (size_t)25165824; // 16,777,216
  unsigned short* C1    = Wob + (size_t)16777216;   // 25,165,824
  unsigned short* Qb    = C1 + (size_t)25165824;    // 16,777,216
  unsigned short* Kb    = Qb + (size_t)16777216;    //  4,194,304
  unsigned short* Vt    = Kb + (size_t)4194304;     //  4,194,304
  unsigned short* AO    = Vt + (size_t)4194304;     // 16,777,216

  // fp32 -> bf16
  cvt_bf16<<<16384, 256, 0, stream>>>(hidden, Xb, 4194304);
  cvt_bf16<<<16384, 256, 0, stream>>>(Wq, Wqkvb, 4194304);
  cvt_bf16<<<4096, 256, 0, stream>>>(Wk, Wqkvb + (size_t)16777216, 1048576);
  cvt_bf16<<<4096, 256, 0, stream>>>(Wv, Wqkvb + (size_t)20971520, 1048576);
  cvt_bf16<<<16384, 256, 0, stream>>>(Wo, Wob, 4194304);

  // QKV projection: [4096,4096] x [6144,4096]^T -> bf16 C1
  gemm_nt<1><<<dim3(48, 32), 256, 0, stream>>>(Xb, Wqkvb, nullptr, C1, 4096, 6144, 4096);

  // RoPE (Q,K heads) + head-major layout
  rope_cvt<<<40960, 256, 0, stream>>>(C1, pos, Qb, Kb);

  // V transpose (no rope): C1 cols 5120.. -> Vt[b,kvh][128][2048]
  vtrans<<<dim3(32, 2, 16), 256, 0, stream>>>(C1, Vt);

  // flash attention, paired q-tiles for balance
  flash_fwd<<<dim3(16, 32, 2), 256, 0, stream>>>(Qb, Kb, Vt, AO);

  // suppression fixup (64 rows recomputed exactly)
  suppress_fix<<<dim3(32, 2), 256, 0, stream>>>(Qb, Kb, Vt, tgt, subj, AO);

  // output projection: [4096,4096] x [4096,4096]^T -> fp32 out
  gemm_nt<0><<<dim3(32, 32), 256, 0, stream>>>(AO, Wob, out, nullptr, 4096, 4096, 4096);
}

// Round 3
// 773.164 us; speedup vs baseline: 1.6975x; 1.0287x over previous
//
#include <hip/hip_runtime.h>
#include <math.h>

typedef float f32x4 __attribute__((ext_vector_type(4)));
typedef unsigned int u32x4 __attribute__((ext_vector_type(4)));
typedef unsigned short u16x4 __attribute__((ext_vector_type(4)));
typedef __bf16 bf16x8 __attribute__((ext_vector_type(8)));

#define SCALE_Q 0.08838834764831845f   // 1/sqrt(128)

__device__ __forceinline__ float bf2f(unsigned short u) {
  unsigned int x = ((unsigned int)u) << 16;
  return __builtin_bit_cast(float, x);
}
__device__ __forceinline__ unsigned short f2bf(float f) {
  unsigned int u = __builtin_bit_cast(unsigned int, f);
  u += 0x7fffu + ((u >> 16) & 1u);
  return (unsigned short)(u >> 16);
}

// async global->LDS, 16B per lane; lds dest must be wave-uniform base (HW adds lane*16)
__device__ __forceinline__ void gload_lds16(const unsigned short* g, unsigned short* l) {
  __builtin_amdgcn_global_load_lds((const __attribute__((address_space(1))) unsigned int*)g,
                                   (__attribute__((address_space(3))) unsigned int*)l,
                                   16, 0, 0);
}

// ---------------- fp32 -> bf16 conversion (vectorized) ----------------
__global__ __launch_bounds__(256) void cvt_bf16(const float* __restrict__ in,
                                                unsigned short* __restrict__ out, int n4) {
  int i = blockIdx.x * 256 + threadIdx.x;
  if (i >= n4) return;
  f32x4 v = *(const f32x4*)(in + (size_t)i * 4);
  u16x4 o;
  o[0] = f2bf(v[0]); o[1] = f2bf(v[1]); o[2] = f2bf(v[2]); o[3] = f2bf(v[3]);
  *(u16x4*)(out + (size_t)i * 4) = o;
}

// =================== 256x256 GEMM, BK=64, 8 waves, swizzled LDS ===============
// C[M,N] = A[M,K] * B[N,K]^T, bf16 in, fp32 acc.
// LDS (dynamic 128 KB): buf b at b*32768 elems: A-tile 32 subtiles of 512 elems,
// then B-tile at +16384. Subtile (R=r>>4, C=c>>5) holds 16 rows x 32 cols with
// st_16x32 swizzle: elem addr = S*512 + (r&15)*32 + ((c&31) ^ (((r&15)>>3)<<4)).
// Staging writes linearly (global_load_lds); the global SOURCE col is
// pre-swizzled: lane l -> row (S>>1)*16 + (l>>2), col (S&1)*32 + ((l&3)*8 ^ ((l>>5)<<4)).
// (Verified involution: read formula recovers A[r][c] exactly.)

__device__ __forceinline__ void stage8(const unsigned short* const* as,
                                       const unsigned short* const* bs,
                                       unsigned short* la, unsigned short* lb, int koff) {
#pragma unroll
  for (int j = 0; j < 4; ++j) {
    gload_lds16(as[j] + koff, la + j * 512);
    gload_lds16(bs[j] + koff, lb + j * 512);
  }
}

template <int BF16OUT>
__global__ __launch_bounds__(512, 2) void gemm256(const unsigned short* __restrict__ A,
                                                  const unsigned short* __restrict__ B,
                                                  float* __restrict__ Cf,
                                                  unsigned short* __restrict__ Cb,
                                                  int M, int N, int K) {
  extern __shared__ __align__(16) unsigned short lds[];
  const int tid = threadIdx.x, lane = tid & 63, wv = tid >> 6;
  const int l16 = lane & 15, g16 = lane >> 4;
  const int m0 = blockIdx.y * 256, n0 = blockIdx.x * 256;
  const int wm = (wv >> 2) * 128, wn = (wv & 3) * 64;

  // staging source pointers: wave stages A-subtiles {4w..4w+3} and same B ones
  const int swzc = ((lane & 3) * 8) ^ ((lane >> 5) << 4);
  const unsigned short* as[4];
  const unsigned short* bs[4];
#pragma unroll
  for (int j = 0; j < 4; ++j) {
    int S = wv * 4 + j;
    int r = (S >> 1) * 16 + (lane >> 2);
    int c = (S & 1) * 32 + swzc;
    as[j] = A + (size_t)(m0 + r) * K + c;
    bs[j] = B + (size_t)(n0 + r) * K + c;
  }
  unsigned short* la0 = lds + wv * 2048;            // buf0 A dest (wave's 4 subtiles)
  unsigned short* lb0 = la0 + 16384;
  unsigned short* la1 = la0 + 32768;                // buf1
  unsigned short* lb1 = lb0 + 32768;

  f32x4 acc[8][4] = {};

  const int NT = K >> 6;
  stage8(as, bs, la0, lb0, 0);     // K-tile 0 -> buf0   (8 loads)
  stage8(as, bs, la1, lb1, 64);    // K-tile 1 -> buf1   (16 outstanding)

  // within-subtile read offset for this lane (elems)
  const int rdo = l16 * 32 + ((g16 * 8) ^ ((l16 >> 3) << 4));

  for (int t = 0; t < NT; ++t) {
    const int cur = t & 1;
    asm volatile("s_waitcnt vmcnt(8)" ::: "memory");  // own 8 loads of tile t landed
    __builtin_amdgcn_s_barrier();                     // => all waves' loads landed
    const unsigned short* La = lds + cur * 32768;
    const unsigned short* Lb = La + 16384;

    // hoist B fragments (8 x ds_read_b128)
    bf16x8 bfr[4][2];
#pragma unroll
    for (int ni = 0; ni < 4; ++ni) {
      int sb = ((wn + ni * 16) >> 4) * 2;
#pragma unroll
      for (int ks = 0; ks < 2; ++ks)
        bfr[ni][ks] = *(const bf16x8*)&Lb[(sb + ks) * 512 + rdo];
    }
    // 4 phases: 4 ds_read_b128 + 16 MFMA each
#pragma unroll
    for (int q = 0; q < 4; ++q) {
      bf16x8 afr[2][2];
#pragma unroll
      for (int j = 0; j < 2; ++j) {
        int sb = ((wm + (q * 2 + j) * 16) >> 4) * 2;
#pragma unroll
        for (int ks = 0; ks < 2; ++ks)
          afr[j][ks] = *(const bf16x8*)&La[(sb + ks) * 512 + rdo];
      }
      __builtin_amdgcn_s_setprio(1);
#pragma unroll
      for (int j = 0; j < 2; ++j)
#pragma unroll
        for (int ni = 0; ni < 4; ++ni)
#pragma unroll
          for (int ks = 0; ks < 2; ++ks)
            acc[q * 2 + j][ni] = __builtin_amdgcn_mfma_f32_16x16x32_bf16(
                afr[j][ks], bfr[ni][ks], acc[q * 2 + j][ni], 0, 0, 0);
      __builtin_amdgcn_s_setprio(0);
    }
    asm volatile("s_waitcnt lgkmcnt(0)" ::: "memory");  // all my LDS reads done
    __builtin_amdgcn_sched_barrier(0);
    __builtin_amdgcn_s_barrier();                       // all waves done reading buf[cur]
    // stage K-tile t+2 into buf[cur] (clamped at the tail: garbage never read)
    int tn = (t + 2 < NT) ? (t + 2) : (NT - 1);
    if (cur == 0) stage8(as, bs, la0, lb0, tn * 64);
    else          stage8(as, bs, la1, lb1, tn * 64);
  }
  asm volatile("s_waitcnt vmcnt(0)" ::: "memory");  // drain tail DMAs before LDS dealloc

#pragma unroll
  for (int mi = 0; mi < 8; ++mi)
#pragma unroll
    for (int ni = 0; ni < 4; ++ni) {
      int row = m0 + wm + mi * 16 + g16 * 4;
      int col = n0 + wn + ni * 16 + l16;
#pragma unroll
      for (int r = 0; r < 4; ++r) {
        if (BF16OUT) Cb[(size_t)(row + r) * N + col] = f2bf(acc[mi][ni][r]);
        else         Cf[(size_t)(row + r) * N + col] = acc[mi][ni][r];
      }
    }
}

// ---------------- RoPE + layout: C1[M,6144] -> Q(B,32,S,HD), K(B,8,S,HD) -------
__global__ __launch_bounds__(256) void rope_cvt(const unsigned short* __restrict__ C1,
                                                const int* __restrict__ pos_ids,
                                                unsigned short* __restrict__ Qb,
                                                unsigned short* __restrict__ Kb) {
  int idx = blockIdx.x * 256 + threadIdx.x;  // total 4096*40*64 = 10,485,760
  int i = idx & 63;
  int t = idx >> 6;
  int head = t % 40;
  int m = t / 40;          // 0..4095 == b*2048 + s
  int b = m >> 11, s = m & 2047;
  const unsigned short* src = C1 + (size_t)m * 6144 + head * 128;
  float x1 = bf2f(src[i]), x2 = bf2f(src[i + 64]);
  float invf = exp2f((float)i * -0.2076205059304601f);  // 10000^(-i/64)
  float ang = (float)pos_ids[m] * invf;
  float c, sn;
  sincosf(ang, &sn, &c);
  float o1 = x1 * c - x2 * sn;
  float o2 = x2 * c + x1 * sn;
  unsigned short* dst;
  if (head < 32)
    dst = Qb + ((size_t)(b * 32 + head) * 2048 + s) * 128;
  else
    dst = Kb + ((size_t)(b * 8 + head - 32) * 2048 + s) * 128;
  dst[i] = f2bf(o1);
  dst[i + 64] = f2bf(o2);
}

// ---------------- V transpose: C1 V-heads -> Vt[b,kvh][d=128][s=2048] ----------
__global__ __launch_bounds__(256) void vtrans(const unsigned short* __restrict__ C1,
                                              unsigned short* __restrict__ Vt) {
  __shared__ __align__(16) unsigned short T[64 * 72];
  const int s0 = blockIdx.x * 64, d0 = blockIdx.y * 64, bh = blockIdx.z;  // bh=b*8+kvh
  const int t = threadIdx.x;
  {
    int sl = t >> 2, c16 = (t & 3) * 16;
    const unsigned short* src =
        C1 + (size_t)((bh >> 3) * 2048 + s0 + sl) * 6144 + 5120 + (bh & 7) * 128 + d0 + c16;
    u32x4 a0 = *(const u32x4*)src;
    u32x4 a1 = *(const u32x4*)(src + 8);
    *(u32x4*)&T[sl * 72 + c16] = a0;
    *(u32x4*)&T[sl * 72 + c16 + 8] = a1;
  }
  __syncthreads();
  {
    int dl = t >> 2, s16 = (t & 3) * 16;
    unsigned short* dst = Vt + ((size_t)bh * 128 + d0 + dl) * 2048 + s0 + s16;
    u16x4 o[4];
#pragma unroll
    for (int j = 0; j < 16; ++j) ((unsigned short*)o)[j] = T[(s16 + j) * 72 + dl];
#pragma unroll
    for (int q = 0; q < 4; ++q) *(u16x4*)(dst + q * 4) = o[q];
  }
}

// ---------------- Flash attention (causal, GQA), 4 waves, QBLK=64, KVBLK=64 ----
// paired q-tiles {31-x, x} for load balance; VT staged from pre-transposed Vt.
__global__ __launch_bounds__(256) void flash_fwd(const unsigned short* __restrict__ Q,
                                                 const unsigned short* __restrict__ K,
                                                 const unsigned short* __restrict__ Vt,
                                                 unsigned short* __restrict__ AO) {
  __shared__ __align__(16) unsigned short Ks[64 * 128];  // [k][d], 256B rows, XOR swz
  __shared__ __align__(16) unsigned short VT[128 * 64];  // [d][k], 128B rows, XOR swz
  __shared__ __align__(16) unsigned short Pl[64 * 72];   // [q][k] pad 72
  const int qpair = blockIdx.x, h = blockIdx.y, b = blockIdx.z;
  const int tid = threadIdx.x, lane = tid & 63, wv = tid >> 6;
  const int l16 = lane & 15, g16 = lane >> 4;
  const unsigned short* Qp = Q + (size_t)(b * 32 + h) * 2048 * 128;
  const unsigned short* Kp = K + (size_t)(b * 8 + (h >> 2)) * 2048 * 128;
  const unsigned short* Vp = Vt + (size_t)(b * 8 + (h >> 2)) * 128 * 2048;

  const int st_row = tid >> 4;        // 0..15
  const int st_cb = (tid & 15) * 16;  // byte col in 256B K row
  const int vd = tid >> 1;            // 0..127  (V d-row)
  const int vh = tid & 1;             // 64B half of 128B V row

  for (int pass = 0; pass < 2; ++pass) {
    const int qt = pass == 0 ? (31 - qpair) : qpair;

    bf16x8 qf[4];
    {
      int qrow = qt * 64 + wv * 16 + l16;
#pragma unroll
      for (int ks = 0; ks < 4; ++ks)
        qf[ks] = *(const bf16x8*)&Qp[(size_t)qrow * 128 + ks * 32 + g16 * 8];
    }

    float m_r[4] = {-1e30f, -1e30f, -1e30f, -1e30f};
    float l_r[4] = {0.f, 0.f, 0.f, 0.f};
    f32x4 ao[8] = {};

    for (int kb = 0; kb <= qt; ++kb) {
      __syncthreads();  // protect Ks/VT from previous iteration/pass readers
      // stage K tile: phys = row*256 + (cb ^ ((row&7)<<4))
#pragma unroll
      for (int p = 0; p < 4; ++p) {
        int row = p * 16 + st_row;
        u32x4 v = *(const u32x4*)&Kp[(size_t)(kb * 64 + row) * 128 + (st_cb >> 1)];
        *(u32x4*)((char*)Ks + row * 256 + (st_cb ^ ((row & 7) << 4))) = v;
      }
      // stage V tile from Vt (rows are d, 64 k-elems = 128B, XOR swz bits 4-6)
#pragma unroll
      for (int j = 0; j < 4; ++j) {
        u32x4 v = *(const u32x4*)&Vp[(size_t)vd * 2048 + kb * 64 + vh * 32 + j * 8];
        *(u32x4*)((char*)VT + vd * 128 + ((vh * 64 + j * 16) ^ ((vd & 7) << 4))) = v;
      }
      __syncthreads();

      // QK^T : S[16q x 64k] per wave
      f32x4 sc[4] = {};
#pragma unroll
      for (int kt = 0; kt < 4; ++kt) {
#pragma unroll
        for (int ks = 0; ks < 4; ++ks) {
          int row = kt * 16 + l16;
          int cb = ks * 64 + g16 * 16;
          bf16x8 kf = *(const bf16x8*)((const char*)Ks + row * 256 + (cb ^ ((row & 7) << 4)));
          sc[kt] = __builtin_amdgcn_mfma_f32_16x16x32_bf16(qf[ks], kf, sc[kt], 0, 0, 0);
        }
      }

      // scale + causal mask
      int qrow0 = qt * 64 + wv * 16 + g16 * 4;
      float p_[4][4];
#pragma unroll
      for (int kt = 0; kt < 4; ++kt)
#pragma unroll
        for (int r = 0; r < 4; ++r) {
          float s = sc[kt][r] * SCALE_Q;
          int kc = kb * 64 + kt * 16 + l16;
          p_[kt][r] = (kc <= qrow0 + r) ? s : -INFINITY;
        }

      // online softmax (row spread over 16-lane group)
#pragma unroll
      for (int r = 0; r < 4; ++r) {
        float mx = fmaxf(fmaxf(p_[0][r], p_[1][r]), fmaxf(p_[2][r], p_[3][r]));
#pragma unroll
        for (int off = 8; off; off >>= 1) mx = fmaxf(mx, __shfl_xor(mx, off));
        float mnew = fmaxf(m_r[r], mx);
        float resc = __expf(m_r[r] - mnew);
        m_r[r] = mnew;
        float rsum = 0.f;
#pragma unroll
        for (int kt = 0; kt < 4; ++kt) {
          float e = __expf(p_[kt][r] - mnew);
          p_[kt][r] = e;
          rsum += e;
        }
#pragma unroll
        for (int off = 8; off; off >>= 1) rsum += __shfl_xor(rsum, off);
        l_r[r] = l_r[r] * resc + rsum;
#pragma unroll
        for (int dt = 0; dt < 8; ++dt) ao[dt][r] *= resc;
      }

      // P -> LDS (per-wave slice), re-layout for PV A-operand
#pragma unroll
      for (int kt = 0; kt < 4; ++kt)
#pragma unroll
        for (int r = 0; r < 4; ++r)
          Pl[(wv * 16 + g16 * 4 + r) * 72 + kt * 16 + l16] = f2bf(p_[kt][r]);

      bf16x8 pa[2];
#pragma unroll
      for (int kc = 0; kc < 2; ++kc)
        pa[kc] = *(const bf16x8*)&Pl[(wv * 16 + l16) * 72 + kc * 32 + g16 * 8];

      // PV: O[16q x 128d] accumulate; VT read with matching XOR swz
#pragma unroll
      for (int dt = 0; dt < 8; ++dt) {
#pragma unroll
        for (int kc = 0; kc < 2; ++kc) {
          bf16x8 vf = *(const bf16x8*)((const char*)VT + (dt * 16 + l16) * 128 +
                                       ((kc * 64 + g16 * 16) ^ ((l16 & 7) << 4)));
          ao[dt] = __builtin_amdgcn_mfma_f32_16x16x32_bf16(pa[kc], vf, ao[dt], 0, 0, 0);
        }
      }
    }

    // write normalized output: AO[b, q, h*128 + d]
    int qrow = qt * 64 + wv * 16 + g16 * 4;
#pragma unroll
    for (int r = 0; r < 4; ++r) {
      float inv = 1.0f / l_r[r];
#pragma unroll
      for (int dt = 0; dt < 8; ++dt)
        AO[((size_t)b * 2048 + qrow + r) * 4096 + h * 128 + dt * 16 + l16] =
            f2bf(ao[dt][r] * inv);
    }
  }
}

// ---------------- suppression fixup: recompute row tgt_pos[b] for every head ---
__global__ __launch_bounds__(256) void suppress_fix(const unsigned short* __restrict__ Q,
                                                    const unsigned short* __restrict__ K,
                                                    const unsigned short* __restrict__ Vt,
                                                    const int* __restrict__ tgt,
                                                    const int* __restrict__ subj,
                                                    unsigned short* __restrict__ AO) {
  const int h = blockIdx.x, b = blockIdx.y;
  const int tid = threadIdx.x, lane = tid & 63, wv = tid >> 6;
  __shared__ float qv[128];
  __shared__ float warr[2048];
  __shared__ float sred[4];
  int row = tgt[b];
  const unsigned short* Qp = Q + ((size_t)(b * 32 + h) * 2048 + row) * 128;
  const unsigned short* Kp = K + (size_t)(b * 8 + (h >> 2)) * 2048 * 128;
  const unsigned short* Vp = Vt + (size_t)(b * 8 + (h >> 2)) * 128 * 2048;
  if (tid < 128) qv[tid] = bf2f(Qp[tid]) * SCALE_Q;
  __syncthreads();
  int nk = row + 1;
  float lmax = -1e30f;
  for (int j = tid; j < nk; j += 256) {
    const unsigned short* kr = Kp + (size_t)j * 128;
    float s = 0.f;
    for (int d = 0; d < 128; d += 8) {
      u32x4 kv = *(const u32x4*)&kr[d];
      const unsigned short* kk = (const unsigned short*)&kv;
#pragma unroll
      for (int e = 0; e < 8; ++e) s += qv[d + e] * bf2f(kk[e]);
    }
    warr[j] = s;
    lmax = fmaxf(lmax, s);
  }
#pragma unroll
  for (int off = 32; off; off >>= 1) lmax = fmaxf(lmax, __shfl_xor(lmax, off));
  if (lane == 0) sred[wv] = lmax;
  __syncthreads();
  float mx = fmaxf(fmaxf(sred[0], sred[1]), fmaxf(sred[2], sred[3]));
  __syncthreads();
  float lsum = 0.f;
  for (int j = tid; j < nk; j += 256) {
    float w = __expf(warr[j] - mx);
    lsum += w;
    float f = 1.f;
#pragma unroll
    for (int i2 = 0; i2 < 8; ++i2)
      if (subj[b * 8 + i2] == j) f *= 0.1f;  // handles duplicate indices
    warr[j] = w * f;
  }
#pragma unroll
  for (int off = 32; off; off >>= 1) lsum += __shfl_xor(lsum, off);
  if (lane == 0) sred[wv] = lsum;
  __syncthreads();
  float tot = sred[0] + sred[1] + sred[2] + sred[3];
  if (tid < 128) {
    float acc = 0.f;
    const unsigned short* vr = Vp + (size_t)tid * 2048;  // row d=tid, contiguous k
    int nk8 = nk & ~7;
    for (int j0 = 0; j0 < nk8; j0 += 8) {
      u32x4 vv = *(const u32x4*)&vr[j0];
      const unsigned short* v8 = (const unsigned short*)&vv;
#pragma unroll
      for (int e = 0; e < 8; ++e) acc += warr[j0 + e] * bf2f(v8[e]);
    }
    for (int j = nk8; j < nk; ++j) acc += warr[j] * bf2f(vr[j]);
    AO[((size_t)b * 2048 + row) * 4096 + h * 128 + tid] = f2bf(acc / tot);
  }
}

// ---------------- launch ----------------
extern "C" void kernel_launch(void* const* d_in, const int* in_sizes, int n_in,
                              void* d_out, int out_size, void* d_ws, size_t ws_size,
                              hipStream_t stream) {
  const float* hidden = (const float*)d_in[0];
  const float* Wq = (const float*)d_in[1];
  const float* Wk = (const float*)d_in[2];
  const float* Wv = (const float*)d_in[3];
  const float* Wo = (const float*)d_in[4];
  // d_in[5] = attention_mask: deterministically causal, not read
  const int* pos = (const int*)d_in[6];
  const int* tgt = (const int*)d_in[7];
  const int* subj = (const int*)d_in[8];
  float* out = (float*)d_out;

  unsigned short* ws = (unsigned short*)d_ws;
  unsigned short* Xb    = ws;                       // 16,777,216
  unsigned short* Wqkvb = Xb + (size_t)16777216;    // 25,165,824
  unsigned short* Wob   = Wqkvb + (size_t)25165824; // 16,777,216
  unsigned short* C1    = Wob + (size_t)16777216;   // 25,165,824
  unsigned short* Qb    = C1 + (size_t)25165824;    // 16,777,216
  unsigned short* Kb    = Qb + (size_t)16777216;    //  4,194,304
  unsigned short* Vt    = Kb + (size_t)4194304;     //  4,194,304
  unsigned short* AO    = Vt + (size_t)4194304;     // 16,777,216

  // allow 128 KB dynamic LDS for the GEMMs (ignore errors; harmless if already set)
  (void)hipFuncSetAttribute(reinterpret_cast<const void*>(gemm256<1>),
                            hipFuncAttributeMaxDynamicSharedMemorySize, 131072);
  (void)hipFuncSetAttribute(reinterpret_cast<const void*>(gemm256<0>),
                            hipFuncAttributeMaxDynamicSharedMemorySize, 131072);

  // fp32 -> bf16
  cvt_bf16<<<16384, 256, 0, stream>>>(hidden, Xb, 4194304);
  cvt_bf16<<<16384, 256, 0, stream>>>(Wq, Wqkvb, 4194304);
  cvt_bf16<<<4096, 256, 0, stream>>>(Wk, Wqkvb + (size_t)16777216, 1048576);
  cvt_bf16<<<4096, 256, 0, stream>>>(Wv, Wqkvb + (size_t)20971520, 1048576);
  cvt_bf16<<<16384, 256, 0, stream>>>(Wo, Wob, 4194304);

  // QKV projection: [4096,4096] x [6144,4096]^T -> bf16 C1
  gemm256<1><<<dim3(24, 16), 512, 131072, stream>>>(Xb, Wqkvb, nullptr, C1, 4096, 6144, 4096);

  // RoPE (Q,K heads) + head-major layout
  rope_cvt<<<40960, 256, 0, stream>>>(C1, pos, Qb, Kb);

  // V transpose (no rope): C1 cols 5120.. -> Vt[b,kvh][128][2048]
  vtrans<<<dim3(32, 2, 16), 256, 0, stream>>>(C1, Vt);

  // flash attention, paired q-tiles for balance
  flash_fwd<<<dim3(16, 32, 2), 256, 0, stream>>>(Qb, Kb, Vt, AO);

  // suppression fixup (64 rows recomputed exactly)
  suppress_fix<<<dim3(32, 2), 256, 0, stream>>>(Qb, Kb, Vt, tgt, subj, AO);

  // output projection: [4096,4096] x [4096,4096]^T -> fp32 out
  gemm256<0><<<dim3(16, 16), 512, 131072, stream>>>(AO, Wob, out, nullptr, 4096, 4096, 4096);
}

// Round 4
// 677.742 us; speedup vs baseline: 1.9365x; 1.1408x over previous
//
#include <hip/hip_runtime.h>
#include <math.h>

typedef float f32x4 __attribute__((ext_vector_type(4)));
typedef unsigned int u32x4 __attribute__((ext_vector_type(4)));
typedef unsigned short u16x4 __attribute__((ext_vector_type(4)));
typedef __bf16 bf16x8 __attribute__((ext_vector_type(8)));

#define SCALE_Q 0.08838834764831845f   // 1/sqrt(128)

__device__ __forceinline__ float bf2f(unsigned short u) {
  unsigned int x = ((unsigned int)u) << 16;
  return __builtin_bit_cast(float, x);
}
__device__ __forceinline__ unsigned short f2bf(float f) {
  unsigned int u = __builtin_bit_cast(unsigned int, f);
  u += 0x7fffu + ((u >> 16) & 1u);
  return (unsigned short)(u >> 16);
}

// async global->LDS, 16B per lane; lds dest must be wave-uniform base (HW adds lane*16)
__device__ __forceinline__ void gload_lds16(const unsigned short* g, unsigned short* l) {
  __builtin_amdgcn_global_load_lds((const __attribute__((address_space(1))) unsigned int*)g,
                                   (__attribute__((address_space(3))) unsigned int*)l,
                                   16, 0, 0);
}

// ---------------- fp32 -> bf16 conversion (vectorized) ----------------
__global__ __launch_bounds__(256) void cvt_bf16(const float* __restrict__ in,
                                                unsigned short* __restrict__ out, int n4) {
  int i = blockIdx.x * 256 + threadIdx.x;
  if (i >= n4) return;
  f32x4 v = *(const f32x4*)(in + (size_t)i * 4);
  u16x4 o;
  o[0] = f2bf(v[0]); o[1] = f2bf(v[1]); o[2] = f2bf(v[2]); o[3] = f2bf(v[3]);
  *(u16x4*)(out + (size_t)i * 4) = o;
}

// =================== 256x256 GEMM, BK=64, 8 waves, 4-phase pipelined ==========
// C[M,N] = A[M,K] * B[N,K]^T, bf16 in, fp32 acc.
// LDS 128 KB: 2 buffers of 32768 elems; buffer = A (32 subtiles x 512) + B same
// at +16384. Subtile S=(r>>4)*2+(c>>5); elem = S*512 + (r&15)*32 + ((c&31)^(((r&15)>>3)<<4)).
// Staging: linear LDS dest (global_load_lds), pre-swizzled global source col.
// Consumption: B fully read at phase 0; A-region-q (subtiles {4q..4q+3} U {16+4q..})
// read only at phase q. Stage slots (2 gloads each, one per phase):
//   phase-0 top: {A3,B3}(t+1) -> other buf   (regions freed by t-1 trailing barrier)
//   phase-q top (q>=1): {A(q-1),B(q-1)}(t+2) -> current buf (freed at phase q-1)
// vmcnt(6) once per tile at phase 3 = wait for {A3,B3}(t+1), 3 slots in flight.

template <int BF16OUT>
__global__ __launch_bounds__(512, 2) void gemm256(const unsigned short* __restrict__ A,
                                                  const unsigned short* __restrict__ B,
                                                  float* __restrict__ Cf,
                                                  unsigned short* __restrict__ Cb,
                                                  int M, int N, int K) {
  extern __shared__ __align__(16) unsigned short lds[];
  const int tid = threadIdx.x, lane = tid & 63, wv = tid >> 6;
  const int l16 = lane & 15, g16 = lane >> 4;
  const int m0 = blockIdx.y * 256, n0 = blockIdx.x * 256;
  const int wm = (wv >> 2) * 128, wn = (wv & 3) * 64;

  // per-slot staging sources and LDS dests
  const unsigned short* aptr[4];
  const unsigned short* bptr[4];
  int adst[4], bdst[4];
#pragma unroll
  for (int j = 0; j < 4; ++j) {
    int S = (wv < 4) ? (4 * j + wv) : (16 + 4 * j + (wv - 4));
    int row = (S >> 1) * 16 + (lane >> 2);
    int col = (S & 1) * 32 + (((lane & 3) * 8) ^ ((lane >> 5) << 4));
    aptr[j] = A + (size_t)(m0 + row) * K + col;
    bptr[j] = B + (size_t)(n0 + row) * K + col;
    adst[j] = S * 512;
    bdst[j] = 16384 + S * 512;
  }

#define SLOT(j, bufoff, koff)                              \
  do {                                                     \
    gload_lds16(aptr[j] + (koff), lds + (bufoff) + adst[j]); \
    gload_lds16(bptr[j] + (koff), lds + (bufoff) + bdst[j]); \
  } while (0)

  f32x4 acc[8][4] = {};
  const int NT = K >> 6;

  // prologue: tile0 fully, tile1 slots 0..2  (14 loads/thread)
  SLOT(0, 0, 0); SLOT(1, 0, 0); SLOT(2, 0, 0); SLOT(3, 0, 0);
  SLOT(0, 32768, 64); SLOT(1, 32768, 64); SLOT(2, 32768, 64);
  asm volatile("s_waitcnt vmcnt(6)" ::: "memory");  // tile0's 8 landed
  __builtin_amdgcn_s_barrier();

  // within-subtile read offset for this lane (elems)
  const int rdo = l16 * 32 + ((g16 * 8) ^ ((l16 >> 3) << 4));

  for (int t = 0; t < NT; ++t) {
    const int p = t & 1;
    const unsigned short* La = lds + p * 32768;
    const unsigned short* Lb = La + 16384;
    const int cur = p * 32768, oth = 32768 - cur;
    const int kn1 = ((t + 1 < NT) ? t + 1 : NT - 1) * 64;
    const int kn2 = ((t + 2 < NT) ? t + 2 : NT - 1) * 64;

    bf16x8 bfr[4][2];

    // -------- phase 0: 8 B-frags + 4 A-frags, slot {A3,B3}(t+1) --------
    {
#pragma unroll
      for (int ni = 0; ni < 4; ++ni) {
        int sb = ((wn + ni * 16) >> 4) * 2;
#pragma unroll
        for (int ks = 0; ks < 2; ++ks)
          bfr[ni][ks] = *(const bf16x8*)&Lb[(sb + ks) * 512 + rdo];
      }
      bf16x8 afr[2][2];
#pragma unroll
      for (int j = 0; j < 2; ++j) {
        int sb = ((wm + j * 16) >> 4) * 2;
#pragma unroll
        for (int ks = 0; ks < 2; ++ks)
          afr[j][ks] = *(const bf16x8*)&La[(sb + ks) * 512 + rdo];
      }
      SLOT(3, oth, kn1);
      __builtin_amdgcn_s_barrier();
      asm volatile("s_waitcnt lgkmcnt(0)" ::: "memory");
      __builtin_amdgcn_s_setprio(1);
#pragma unroll
      for (int j = 0; j < 2; ++j)
#pragma unroll
        for (int ni = 0; ni < 4; ++ni)
#pragma unroll
          for (int ks = 0; ks < 2; ++ks)
            acc[j][ni] = __builtin_amdgcn_mfma_f32_16x16x32_bf16(
                afr[j][ks], bfr[ni][ks], acc[j][ni], 0, 0, 0);
      __builtin_amdgcn_s_setprio(0);
      __builtin_amdgcn_s_barrier();
    }

    // -------- phases 1..3: 4 A-frags, slot {A(q-1),B(q-1)}(t+2) --------
#pragma unroll
    for (int q = 1; q < 4; ++q) {
      bf16x8 afr[2][2];
#pragma unroll
      for (int j = 0; j < 2; ++j) {
        int sb = ((wm + (q * 2 + j) * 16) >> 4) * 2;
#pragma unroll
        for (int ks = 0; ks < 2; ++ks)
          afr[j][ks] = *(const bf16x8*)&La[(sb + ks) * 512 + rdo];
      }
      if (q == 1) SLOT(0, cur, kn2);
      if (q == 2) SLOT(1, cur, kn2);
      if (q == 3) {
        SLOT(2, cur, kn2);
        asm volatile("s_waitcnt vmcnt(6)" ::: "memory");  // {A3,B3}(t+1) landed
      }
      __builtin_amdgcn_s_barrier();
      asm volatile("s_waitcnt lgkmcnt(0)" ::: "memory");
      __builtin_amdgcn_s_setprio(1);
#pragma unroll
      for (int j = 0; j < 2; ++j)
#pragma unroll
        for (int ni = 0; ni < 4; ++ni)
#pragma unroll
          for (int ks = 0; ks < 2; ++ks)
            acc[q * 2 + j][ni] = __builtin_amdgcn_mfma_f32_16x16x32_bf16(
                afr[j][ks], bfr[ni][ks], acc[q * 2 + j][ni], 0, 0, 0);
      __builtin_amdgcn_s_setprio(0);
      __builtin_amdgcn_s_barrier();
    }
  }
  asm volatile("s_waitcnt vmcnt(0)" ::: "memory");  // drain tail DMAs
#undef SLOT

#pragma unroll
  for (int mi = 0; mi < 8; ++mi)
#pragma unroll
    for (int ni = 0; ni < 4; ++ni) {
      int row = m0 + wm + mi * 16 + g16 * 4;
      int col = n0 + wn + ni * 16 + l16;
#pragma unroll
      for (int r = 0; r < 4; ++r) {
        if (BF16OUT) Cb[(size_t)(row + r) * N + col] = f2bf(acc[mi][ni][r]);
        else         Cf[(size_t)(row + r) * N + col] = acc[mi][ni][r];
      }
    }
}

// ---------------- RoPE + layout: C1[M,6144] -> Q(B,32,S,HD), K(B,8,S,HD) -------
__global__ __launch_bounds__(256) void rope_cvt(const unsigned short* __restrict__ C1,
                                                const int* __restrict__ pos_ids,
                                                unsigned short* __restrict__ Qb,
                                                unsigned short* __restrict__ Kb) {
  int idx = blockIdx.x * 256 + threadIdx.x;  // total 4096*40*64 = 10,485,760
  int i = idx & 63;
  int t = idx >> 6;
  int head = t % 40;
  int m = t / 40;          // 0..4095 == b*2048 + s
  int b = m >> 11, s = m & 2047;
  const unsigned short* src = C1 + (size_t)m * 6144 + head * 128;
  float x1 = bf2f(src[i]), x2 = bf2f(src[i + 64]);
  float invf = exp2f((float)i * -0.2076205059304601f);  // 10000^(-i/64)
  float ang = (float)pos_ids[m] * invf;
  float c, sn;
  sincosf(ang, &sn, &c);
  float o1 = x1 * c - x2 * sn;
  float o2 = x2 * c + x1 * sn;
  unsigned short* dst;
  if (head < 32)
    dst = Qb + ((size_t)(b * 32 + head) * 2048 + s) * 128;
  else
    dst = Kb + ((size_t)(b * 8 + head - 32) * 2048 + s) * 128;
  dst[i] = f2bf(o1);
  dst[i + 64] = f2bf(o2);
}

// ---------------- V transpose: C1 V-heads -> Vt[b,kvh][d=128][s=2048] ----------
__global__ __launch_bounds__(256) void vtrans(const unsigned short* __restrict__ C1,
                                              unsigned short* __restrict__ Vt) {
  __shared__ __align__(16) unsigned short T[64 * 72];
  const int s0 = blockIdx.x * 64, d0 = blockIdx.y * 64, bh = blockIdx.z;  // bh=b*8+kvh
  const int t = threadIdx.x;
  {
    int sl = t >> 2, c16 = (t & 3) * 16;
    const unsigned short* src =
        C1 + (size_t)((bh >> 3) * 2048 + s0 + sl) * 6144 + 5120 + (bh & 7) * 128 + d0 + c16;
    u32x4 a0 = *(const u32x4*)src;
    u32x4 a1 = *(const u32x4*)(src + 8);
    *(u32x4*)&T[sl * 72 + c16] = a0;
    *(u32x4*)&T[sl * 72 + c16 + 8] = a1;
  }
  __syncthreads();
  {
    int dl = t >> 2, s16 = (t & 3) * 16;
    unsigned short* dst = Vt + ((size_t)bh * 128 + d0 + dl) * 2048 + s0 + s16;
    u16x4 o[4];
#pragma unroll
    for (int j = 0; j < 16; ++j) ((unsigned short*)o)[j] = T[(s16 + j) * 72 + dl];
#pragma unroll
    for (int q = 0; q < 4; ++q) *(u16x4*)(dst + q * 4) = o[q];
  }
}

// ---------------- Flash attention (causal, GQA), 4 waves, QBLK=64, KVBLK=64 ----
// paired q-tiles {31-x, x} for load balance; VT staged from pre-transposed Vt.
__global__ __launch_bounds__(256) void flash_fwd(const unsigned short* __restrict__ Q,
                                                 const unsigned short* __restrict__ K,
                                                 const unsigned short* __restrict__ Vt,
                                                 unsigned short* __restrict__ AO) {
  __shared__ __align__(16) unsigned short Ks[64 * 128];  // [k][d], 256B rows, XOR swz
  __shared__ __align__(16) unsigned short VT[128 * 64];  // [d][k], 128B rows, XOR swz
  __shared__ __align__(16) unsigned short Pl[64 * 72];   // [q][k] pad 72
  const int qpair = blockIdx.x, h = blockIdx.y, b = blockIdx.z;
  const int tid = threadIdx.x, lane = tid & 63, wv = tid >> 6;
  const int l16 = lane & 15, g16 = lane >> 4;
  const unsigned short* Qp = Q + (size_t)(b * 32 + h) * 2048 * 128;
  const unsigned short* Kp = K + (size_t)(b * 8 + (h >> 2)) * 2048 * 128;
  const unsigned short* Vp = Vt + (size_t)(b * 8 + (h >> 2)) * 128 * 2048;

  const int st_row = tid >> 4;        // 0..15
  const int st_cb = (tid & 15) * 16;  // byte col in 256B K row
  const int vd = tid >> 1;            // 0..127  (V d-row)
  const int vh = tid & 1;             // 64B half of 128B V row

  for (int pass = 0; pass < 2; ++pass) {
    const int qt = pass == 0 ? (31 - qpair) : qpair;

    bf16x8 qf[4];
    {
      int qrow = qt * 64 + wv * 16 + l16;
#pragma unroll
      for (int ks = 0; ks < 4; ++ks)
        qf[ks] = *(const bf16x8*)&Qp[(size_t)qrow * 128 + ks * 32 + g16 * 8];
    }

    float m_r[4] = {-1e30f, -1e30f, -1e30f, -1e30f};
    float l_r[4] = {0.f, 0.f, 0.f, 0.f};
    f32x4 ao[8] = {};

    for (int kb = 0; kb <= qt; ++kb) {
      __syncthreads();  // protect Ks/VT from previous iteration/pass readers
      // stage K tile: phys = row*256 + (cb ^ ((row&7)<<4))
#pragma unroll
      for (int p = 0; p < 4; ++p) {
        int row = p * 16 + st_row;
        u32x4 v = *(const u32x4*)&Kp[(size_t)(kb * 64 + row) * 128 + (st_cb >> 1)];
        *(u32x4*)((char*)Ks + row * 256 + (st_cb ^ ((row & 7) << 4))) = v;
      }
      // stage V tile from Vt (rows are d, 64 k-elems = 128B, XOR swz bits 4-6)
#pragma unroll
      for (int j = 0; j < 4; ++j) {
        u32x4 v = *(const u32x4*)&Vp[(size_t)vd * 2048 + kb * 64 + vh * 32 + j * 8];
        *(u32x4*)((char*)VT + vd * 128 + ((vh * 64 + j * 16) ^ ((vd & 7) << 4))) = v;
      }
      __syncthreads();

      // QK^T : S[16q x 64k] per wave
      f32x4 sc[4] = {};
#pragma unroll
      for (int kt = 0; kt < 4; ++kt) {
#pragma unroll
        for (int ks = 0; ks < 4; ++ks) {
          int row = kt * 16 + l16;
          int cb = ks * 64 + g16 * 16;
          bf16x8 kf = *(const bf16x8*)((const char*)Ks + row * 256 + (cb ^ ((row & 7) << 4)));
          sc[kt] = __builtin_amdgcn_mfma_f32_16x16x32_bf16(qf[ks], kf, sc[kt], 0, 0, 0);
        }
      }

      // scale + causal mask
      int qrow0 = qt * 64 + wv * 16 + g16 * 4;
      float p_[4][4];
#pragma unroll
      for (int kt = 0; kt < 4; ++kt)
#pragma unroll
        for (int r = 0; r < 4; ++r) {
          float s = sc[kt][r] * SCALE_Q;
          int kc = kb * 64 + kt * 16 + l16;
          p_[kt][r] = (kc <= qrow0 + r) ? s : -INFINITY;
        }

      // online softmax (row spread over 16-lane group)
#pragma unroll
      for (int r = 0; r < 4; ++r) {
        float mx = fmaxf(fmaxf(p_[0][r], p_[1][r]), fmaxf(p_[2][r], p_[3][r]));
#pragma unroll
        for (int off = 8; off; off >>= 1) mx = fmaxf(mx, __shfl_xor(mx, off));
        float mnew = fmaxf(m_r[r], mx);
        float resc = __expf(m_r[r] - mnew);
        m_r[r] = mnew;
        float rsum = 0.f;
#pragma unroll
        for (int kt = 0; kt < 4; ++kt) {
          float e = __expf(p_[kt][r] - mnew);
          p_[kt][r] = e;
          rsum += e;
        }
#pragma unroll
        for (int off = 8; off; off >>= 1) rsum += __shfl_xor(rsum, off);
        l_r[r] = l_r[r] * resc + rsum;
#pragma unroll
        for (int dt = 0; dt < 8; ++dt) ao[dt][r] *= resc;
      }

      // P -> LDS (per-wave slice), re-layout for PV A-operand
#pragma unroll
      for (int kt = 0; kt < 4; ++kt)
#pragma unroll
        for (int r = 0; r < 4; ++r)
          Pl[(wv * 16 + g16 * 4 + r) * 72 + kt * 16 + l16] = f2bf(p_[kt][r]);

      bf16x8 pa[2];
#pragma unroll
      for (int kc = 0; kc < 2; ++kc)
        pa[kc] = *(const bf16x8*)&Pl[(wv * 16 + l16) * 72 + kc * 32 + g16 * 8];

      // PV: O[16q x 128d] accumulate; VT read with matching XOR swz
#pragma unroll
      for (int dt = 0; dt < 8; ++dt) {
#pragma unroll
        for (int kc = 0; kc < 2; ++kc) {
          bf16x8 vf = *(const bf16x8*)((const char*)VT + (dt * 16 + l16) * 128 +
                                       ((kc * 64 + g16 * 16) ^ ((l16 & 7) << 4)));
          ao[dt] = __builtin_amdgcn_mfma_f32_16x16x32_bf16(pa[kc], vf, ao[dt], 0, 0, 0);
        }
      }
    }

    // write normalized output: AO[b, q, h*128 + d]
    int qrow = qt * 64 + wv * 16 + g16 * 4;
#pragma unroll
    for (int r = 0; r < 4; ++r) {
      float inv = 1.0f / l_r[r];
#pragma unroll
      for (int dt = 0; dt < 8; ++dt)
        AO[((size_t)b * 2048 + qrow + r) * 4096 + h * 128 + dt * 16 + l16] =
            f2bf(ao[dt][r] * inv);
    }
  }
}

// ---------------- suppression fixup: recompute row tgt_pos[b] for every head ---
__global__ __launch_bounds__(256) void suppress_fix(const unsigned short* __restrict__ Q,
                                                    const unsigned short* __restrict__ K,
                                                    const unsigned short* __restrict__ Vt,
                                                    const int* __restrict__ tgt,
                                                    const int* __restrict__ subj,
                                                    unsigned short* __restrict__ AO) {
  const int h = blockIdx.x, b = blockIdx.y;
  const int tid = threadIdx.x, lane = tid & 63, wv = tid >> 6;
  __shared__ float qv[128];
  __shared__ float warr[2048];
  __shared__ float sred[4];
  int row = tgt[b];
  const unsigned short* Qp = Q + ((size_t)(b * 32 + h) * 2048 + row) * 128;
  const unsigned short* Kp = K + (size_t)(b * 8 + (h >> 2)) * 2048 * 128;
  const unsigned short* Vp = Vt + (size_t)(b * 8 + (h >> 2)) * 128 * 2048;
  if (tid < 128) qv[tid] = bf2f(Qp[tid]) * SCALE_Q;
  __syncthreads();
  int nk = row + 1;
  float lmax = -1e30f;
  for (int j = tid; j < nk; j += 256) {
    const unsigned short* kr = Kp + (size_t)j * 128;
    float s = 0.f;
    for (int d = 0; d < 128; d += 8) {
      u32x4 kv = *(const u32x4*)&kr[d];
      const unsigned short* kk = (const unsigned short*)&kv;
#pragma unroll
      for (int e = 0; e < 8; ++e) s += qv[d + e] * bf2f(kk[e]);
    }
    warr[j] = s;
    lmax = fmaxf(lmax, s);
  }
#pragma unroll
  for (int off = 32; off; off >>= 1) lmax = fmaxf(lmax, __shfl_xor(lmax, off));
  if (lane == 0) sred[wv] = lmax;
  __syncthreads();
  float mx = fmaxf(fmaxf(sred[0], sred[1]), fmaxf(sred[2], sred[3]));
  __syncthreads();
  float lsum = 0.f;
  for (int j = tid; j < nk; j += 256) {
    float w = __expf(warr[j] - mx);
    lsum += w;
    float f = 1.f;
#pragma unroll
    for (int i2 = 0; i2 < 8; ++i2)
      if (subj[b * 8 + i2] == j) f *= 0.1f;  // handles duplicate indices
    warr[j] = w * f;
  }
#pragma unroll
  for (int off = 32; off; off >>= 1) lsum += __shfl_xor(lsum, off);
  if (lane == 0) sred[wv] = lsum;
  __syncthreads();
  float tot = sred[0] + sred[1] + sred[2] + sred[3];
  if (tid < 128) {
    float acc = 0.f;
    const unsigned short* vr = Vp + (size_t)tid * 2048;  // row d=tid, contiguous k
    int nk8 = nk & ~7;
    for (int j0 = 0; j0 < nk8; j0 += 8) {
      u32x4 vv = *(const u32x4*)&vr[j0];
      const unsigned short* v8 = (const unsigned short*)&vv;
#pragma unroll
      for (int e = 0; e < 8; ++e) acc += warr[j0 + e] * bf2f(v8[e]);
    }
    for (int j = nk8; j < nk; ++j) acc += warr[j] * bf2f(vr[j]);
    AO[((size_t)b * 2048 + row) * 4096 + h * 128 + tid] = f2bf(acc / tot);
  }
}

// ---------------- launch ----------------
extern "C" void kernel_launch(void* const* d_in, const int* in_sizes, int n_in,
                              void* d_out, int out_size, void* d_ws, size_t ws_size,
                              hipStream_t stream) {
  const float* hidden = (const float*)d_in[0];
  const float* Wq = (const float*)d_in[1];
  const float* Wk = (const float*)d_in[2];
  const float* Wv = (const float*)d_in[3];
  const float* Wo = (const float*)d_in[4];
  // d_in[5] = attention_mask: deterministically causal, not read
  const int* pos = (const int*)d_in[6];
  const int* tgt = (const int*)d_in[7];
  const int* subj = (const int*)d_in[8];
  float* out = (float*)d_out;

  unsigned short* ws = (unsigned short*)d_ws;
  unsigned short* Xb    = ws;                       // 16,777,216
  unsigned short* Wqkvb = Xb + (size_t)16777216;    // 25,165,824
  unsigned short* Wob   = Wqkvb + (size_t)25165824; // 16,777,216
  unsigned short* C1    = Wob + (size_t)16777216;   // 25,165,824
  unsigned short* Qb    = C1 + (size_t)25165824;    // 16,777,216
  unsigned short* Kb    = Qb + (size_t)16777216;    //  4,194,304
  unsigned short* Vt    = Kb + (size_t)4194304;     //  4,194,304
  unsigned short* AO    = Vt + (size_t)4194304;     // 16,777,216

  // allow 128 KB dynamic LDS for the GEMMs
  (void)hipFuncSetAttribute(reinterpret_cast<const void*>(gemm256<1>),
                            hipFuncAttributeMaxDynamicSharedMemorySize, 131072);
  (void)hipFuncSetAttribute(reinterpret_cast<const void*>(gemm256<0>),
                            hipFuncAttributeMaxDynamicSharedMemorySize, 131072);

  // fp32 -> bf16
  cvt_bf16<<<16384, 256, 0, stream>>>(hidden, Xb, 4194304);
  cvt_bf16<<<16384, 256, 0, stream>>>(Wq, Wqkvb, 4194304);
  cvt_bf16<<<4096, 256, 0, stream>>>(Wk, Wqkvb + (size_t)16777216, 1048576);
  cvt_bf16<<<4096, 256, 0, stream>>>(Wv, Wqkvb + (size_t)20971520, 1048576);
  cvt_bf16<<<16384, 256, 0, stream>>>(Wo, Wob, 4194304);

  // QKV projection: [4096,4096] x [6144,4096]^T -> bf16 C1
  gemm256<1><<<dim3(24, 16), 512, 131072, stream>>>(Xb, Wqkvb, nullptr, C1, 4096, 6144, 4096);

  // RoPE (Q,K heads) + head-major layout
  rope_cvt<<<40960, 256, 0, stream>>>(C1, pos, Qb, Kb);

  // V transpose (no rope): C1 cols 5120.. -> Vt[b,kvh][128][2048]
  vtrans<<<dim3(32, 2, 16), 256, 0, stream>>>(C1, Vt);

  // flash attention, paired q-tiles for balance
  flash_fwd<<<dim3(16, 32, 2), 256, 0, stream>>>(Qb, Kb, Vt, AO);

  // suppression fixup (64 rows recomputed exactly)
  suppress_fix<<<dim3(32, 2), 256, 0, stream>>>(Qb, Kb, Vt, tgt, subj, AO);

  // output projection: [4096,4096] x [4096,4096]^T -> fp32 out
  gemm256<0><<<dim3(16, 16), 512, 131072, stream>>>(AO, Wob, out, nullptr, 4096, 4096, 4096);
}